// Round 5
// baseline (325.653 us; speedup 1.0000x reference)
//
#include <hip/hip_runtime.h>
#include <math.h>

#define B_   32
#define N_   8192
#define H_   128
#define G_   10
#define TOKS (B_*N_)
#define THREADS 512
#define WAVES 8
#define TPW 32
#define TPB 256
#define LDW 136   // hids row stride in shorts (272B)

typedef short bf16x8 __attribute__((ext_vector_type(8)));
typedef short bf16x4 __attribute__((ext_vector_type(4)));
typedef float f32x4 __attribute__((ext_vector_type(4)));

// ws layout: [0..1] loss_sum/mask_count floats; weight image at byte WS_IMG_OFF.
// image (shorts unless noted):
//   w1img [3][128][128]  W1^T: [h][j][i]        (98304 shorts)
//   w2img [3][16][128]   W2^T: [h][g pad16][k]  (6144 shorts)
//   b1img [3][128] f32, b2img [3][16] f32
#define WS_IMG_OFF 256
#define IMG_W2   (3*H_*H_)
#define IMG_BF   (IMG_W2 + 3*16*H_)   // float region start (in shorts)
#define IMG_BYTES (IMG_BF*2 + 3*H_*4 + 3*16*4)

__device__ __forceinline__ short f2bf(float f) {
  union { float f; unsigned u; } v; v.f = f;
  unsigned r = v.u + 0x7fffu + ((v.u >> 16) & 1u);  // RNE
  return (short)(r >> 16);
}

__global__ __launch_bounds__(64) void init_kernel(float* out, float* ws) {
  int t = threadIdx.x;
  if (t < 33) out[t] = 0.0f;
  if (t < 2)  ws[t]  = 0.0f;
}

__global__ __launch_bounds__(64) void fin_kernel(float* out, const float* ws) {
  if (threadIdx.x == 0) out[32] = ws[0] / fmaxf(ws[1], 1.0f);
}

__global__ __launch_bounds__(256) void prep_kernel(
    const float* __restrict__ w1_0, const float* __restrict__ b1_0,
    const float* __restrict__ w2_0, const float* __restrict__ b2_0,
    const float* __restrict__ w1_1, const float* __restrict__ b1_1,
    const float* __restrict__ w2_1, const float* __restrict__ b2_1,
    const float* __restrict__ w1_2, const float* __restrict__ b1_2,
    const float* __restrict__ w2_2, const float* __restrict__ b2_2,
    short* __restrict__ img) {
  const float* w1p[3] = {w1_0, w1_1, w1_2};
  const float* w2p[3] = {w2_0, w2_1, w2_2};
  const float* b1p[3] = {b1_0, b1_1, b1_2};
  const float* b2p[3] = {b2_0, b2_1, b2_2};
  int t = blockIdx.x * 256 + threadIdx.x;
  int stride = gridDim.x * 256;
  for (int idx = t; idx < 3*H_*H_; idx += stride) {
    int h = idx / (H_*H_), rem = idx - h*(H_*H_);
    int j = rem >> 7, i = rem & 127;
    img[idx] = f2bf(w1p[h][i*H_ + j]);          // W1^T
  }
  for (int idx = t; idx < 3*16*H_; idx += stride) {
    int h = idx / (16*H_), rem = idx - h*(16*H_);
    int g = rem >> 7, k = rem & 127;
    img[IMG_W2 + idx] = (g < G_) ? f2bf(w2p[h][k*G_ + g]) : (short)0;
  }
  float* bimg = (float*)(img + IMG_BF);
  if (t < 3*H_ + 3*16) {
    if (t < 3*H_) { int h = t >> 7, j = t & 127; bimg[t] = b1p[h][j]; }
    else { int i2 = t - 3*H_; int h = i2 >> 4, g = i2 & 15;
           bimg[t] = (g < G_) ? b2p[h][g] : 0.0f; }
  }
}

template<int PREP>
__global__ __launch_bounds__(THREADS, 8)
void rtm_main(const float* __restrict__ feat,
              const float* __restrict__ dist,
              const int* __restrict__ dmask,
              const short* __restrict__ img,
              const float* __restrict__ w1_0, const float* __restrict__ b1_0,
              const float* __restrict__ w2_0, const float* __restrict__ b2_0,
              const float* __restrict__ w1_1, const float* __restrict__ b1_1,
              const float* __restrict__ w2_1, const float* __restrict__ b2_1,
              const float* __restrict__ w1_2, const float* __restrict__ b1_2,
              const float* __restrict__ w2_2, const float* __restrict__ b2_2,
              float* __restrict__ out, float* __restrict__ ws) {
  __shared__ short hids[WAVES][16][LDW];   // [wave][token][j]
  __shared__ float red[WAVES][3];

  const int tid  = threadIdx.x;
  const int wave = tid >> 6;
  const int lane = tid & 63;
  const int q  = lane >> 4;
  const int lg = lane & 15;
  const long wtok0 = (long)blockIdx.x * TPB + (long)wave * TPW;

  // ---- issue token loads first ----
  float dpre[2]; int mpre[2];
#pragma unroll
  for (int mt = 0; mt < 2; ++mt) {
    long tok = wtok0 + mt*16 + lg;
    dpre[mt] = dist[tok];
    mpre[mt] = dmask[tok];
  }
  float4 fv[2][4][2];
#pragma unroll
  for (int mt = 0; mt < 2; ++mt) {
    const float* fr = feat + (wtok0 + mt*16 + lg) * (long)H_;
#pragma unroll
    for (int c = 0; c < 4; ++c) {
      const float4* p = reinterpret_cast<const float4*>(fr + c*32 + q*8);
      fv[mt][c][0] = p[0];
      fv[mt][c][1] = p[1];
    }
  }
  // features -> bf16 B-fragments: lane holds B[k=(lane>>4)*8+j][tok=lane&15]
  bf16x8 a1[2][4];
#pragma unroll
  for (int mt = 0; mt < 2; ++mt)
#pragma unroll
    for (int c = 0; c < 4; ++c) {
      float4 lo = fv[mt][c][0], hi = fv[mt][c][1];
      bf16x8 a;
      a[0]=f2bf(lo.x); a[1]=f2bf(lo.y); a[2]=f2bf(lo.z); a[3]=f2bf(lo.w);
      a[4]=f2bf(hi.x); a[5]=f2bf(hi.y); a[6]=f2bf(hi.z); a[7]=f2bf(hi.w);
      a1[mt][c] = a;
    }

  const float* bimg = PREP ? (const float*)(img + IMG_BF) : nullptr;
  const float* w1p[3] = {w1_0, w1_1, w1_2};
  const float* w2p[3] = {w2_0, w2_1, w2_2};
  const float* b1p[3] = {b1_0, b1_1, b1_2};
  const float* b2p[3] = {b2_0, b2_1, b2_2};

  // ---- 3 heads; weights read straight from L1/L2-resident image ----
  f32x4 lgt[3][2];
#pragma unroll
  for (int h = 0; h < 3; ++h) {
    // biases
    f32x4 b1v[8];
    f32x4 b2v;
    if constexpr (PREP) {
#pragma unroll
      for (int nt = 0; nt < 8; ++nt)
        b1v[nt] = *reinterpret_cast<const f32x4*>(&bimg[h*H_ + nt*16 + q*4]);
      b2v = *reinterpret_cast<const f32x4*>(&bimg[3*H_ + h*16 + q*4]);
    } else {
#pragma unroll
      for (int nt = 0; nt < 8; ++nt)
#pragma unroll
        for (int r = 0; r < 4; ++r) b1v[nt][r] = b1p[h][nt*16 + q*4 + r];
#pragma unroll
      for (int r = 0; r < 4; ++r) b2v[r] = (q*4+r < G_) ? b2p[h][q*4+r] : 0.0f;
    }
    // W2^T fragments (per h, reused across mt): lane = A[row=g=lg][k=c*32+q*8..]
    bf16x8 w2fr[4];
#pragma unroll
    for (int c = 0; c < 4; ++c) {
      if constexpr (PREP) {
        w2fr[c] = *reinterpret_cast<const bf16x8*>(&img[IMG_W2 + (h*16 + lg)*H_ + c*32 + q*8]);
      } else {
        bf16x8 t;
#pragma unroll
        for (int e = 0; e < 8; ++e)
          t[e] = (lg < G_) ? f2bf(w2p[h][(c*32 + q*8 + e)*G_ + lg]) : (short)0;
        w2fr[c] = t;
      }
    }

    // layer 1: acc[mt][nt], W1 fragment loaded once, feeds both mt
    f32x4 acc[2][8];
#pragma unroll
    for (int mt = 0; mt < 2; ++mt)
#pragma unroll
      for (int nt = 0; nt < 8; ++nt) acc[mt][nt] = (f32x4){0.f,0.f,0.f,0.f};
#pragma unroll
    for (int c = 0; c < 4; ++c) {
#pragma unroll
      for (int nt = 0; nt < 8; ++nt) {
        bf16x8 wfr;
        if constexpr (PREP) {
          wfr = *reinterpret_cast<const bf16x8*>(&img[(h*H_ + nt*16 + lg)*H_ + c*32 + q*8]);
        } else {
#pragma unroll
          for (int e = 0; e < 8; ++e)
            wfr[e] = f2bf(w1p[h][(c*32 + q*8 + e)*H_ + nt*16 + lg]);
        }
        acc[0][nt] = __builtin_amdgcn_mfma_f32_16x16x32_bf16(wfr, a1[0][c], acc[0][nt], 0, 0, 0);
        acc[1][nt] = __builtin_amdgcn_mfma_f32_16x16x32_bf16(wfr, a1[1][c], acc[1][nt], 0, 0, 0);
      }
    }

#pragma unroll
    for (int mt = 0; mt < 2; ++mt) {
      // D: row = j = q*4+r, col = token = lg -> one b64 write per nt
#pragma unroll
      for (int nt = 0; nt < 8; ++nt) {
        bf16x4 pk;
#pragma unroll
        for (int r = 0; r < 4; ++r)
          pk[r] = f2bf(fmaxf(acc[mt][nt][r] + b1v[nt][r], 0.0f));
        *reinterpret_cast<bf16x4*>(&hids[wave][lg][nt*16 + q*4]) = pk;
      }
      // layer 2 (same-wave LDS FIFO ordering; no barrier needed)
      f32x4 lacc = (f32x4){0.f,0.f,0.f,0.f};
#pragma unroll
      for (int c = 0; c < 4; ++c) {
        bf16x8 hfr = *reinterpret_cast<const bf16x8*>(&hids[wave][lg][c*32 + q*8]);
        lacc = __builtin_amdgcn_mfma_f32_16x16x32_bf16(w2fr[c], hfr, lacc, 0, 0, 0);
      }
      lgt[h][mt] = lacc + b2v;   // row = g = q*4+r, col = token = lg
    }
  }

  // ---- epilogue: token = lg; lane holds g = q*4+r ----
  float* out_score = out;
  float* out_pi = out + 33;
  float* out_mu = out + 33 + (size_t)TOKS*G_;
  float* out_sg = out + 33 + 2*(size_t)TOKS*G_;
  const float HLOG2PI = 0.91893853320467274f;

  const bool v0 = (q*4+0) < G_, v1 = (q*4+1) < G_, v2 = (q*4+2) < G_, v3 = (q*4+3) < G_;

  float accP = 0.f, accL = 0.f, accC = 0.f;
#pragma unroll
  for (int mt = 0; mt < 2; ++mt) {
    long tok = wtok0 + mt*16 + lg;
    float d  = dpre[mt];
    bool  mk = (mpre[mt] != 0) && (d <= 8.0f);

    f32x4 LP = lgt[0][mt], LS = lgt[1][mt], LM = lgt[2][mt];

    float vm = v0 ? LP[0] : -INFINITY;
    if (v1) vm = fmaxf(vm, LP[1]);
    if (v2) vm = fmaxf(vm, LP[2]);
    if (v3) vm = fmaxf(vm, LP[3]);
    vm = fmaxf(vm, __shfl_xor(vm, 16));
    vm = fmaxf(vm, __shfl_xor(vm, 32));
    float e0 = v0 ? __expf(LP[0]-vm) : 0.f;
    float e1 = v1 ? __expf(LP[1]-vm) : 0.f;
    float e2 = v2 ? __expf(LP[2]-vm) : 0.f;
    float e3 = v3 ? __expf(LP[3]-vm) : 0.f;
    float s = e0+e1+e2+e3;
    s += __shfl_xor(s, 16);
    s += __shfl_xor(s, 32);
    float inv = 1.0f / s;
    float pi[4] = {e0*inv, e1*inv, e2*inv, e3*inv};

    float sg[4], mu[4], ll[4];
#pragma unroll
    for (int r = 0; r < 4; ++r) {
      sg[r] = (LS[r] > 0.f) ? (LS[r] + 1.4f) : (__expf(LS[r]) + 0.4f);
      mu[r] = (LM[r] > 0.f) ? (LM[r] + 1.0f) : __expf(LM[r]);
      float z = (d - mu[r]) / sg[r];
      ll[r] = -0.5f*z*z - __logf(sg[r]) - HLOG2PI;
    }

    if (q*4 < G_) {
      size_t o = (size_t)tok*G_ + q*4;
      *reinterpret_cast<float2*>(&out_pi[o]) = make_float2(pi[0], pi[1]);
      *reinterpret_cast<float2*>(&out_mu[o]) = make_float2(mu[0], mu[1]);
      *reinterpret_cast<float2*>(&out_sg[o]) = make_float2(sg[0], sg[1]);
      if (q*4+2 < G_) {
        *reinterpret_cast<float2*>(&out_pi[o+2]) = make_float2(pi[2], pi[3]);
        *reinterpret_cast<float2*>(&out_mu[o+2]) = make_float2(mu[2], mu[3]);
        *reinterpret_cast<float2*>(&out_sg[o+2]) = make_float2(sg[2], sg[3]);
      }
    }

    float a0 = v0 ? (__logf(pi[0]+1e-10f) + ll[0]) : -INFINITY;
    float a1x= v1 ? (__logf(pi[1]+1e-10f) + ll[1]) : -INFINITY;
    float a2 = v2 ? (__logf(pi[2]+1e-10f) + ll[2]) : -INFINITY;
    float a3 = v3 ? (__logf(pi[3]+1e-10f) + ll[3]) : -INFINITY;
    float m2 = fmaxf(fmaxf(a0,a1x), fmaxf(a2,a3));
    m2 = fmaxf(m2, __shfl_xor(m2, 16));
    m2 = fmaxf(m2, __shfl_xor(m2, 32));
    float s2 = (v0?__expf(a0-m2):0.f) + (v1?__expf(a1x-m2):0.f)
             + (v2?__expf(a2-m2):0.f) + (v3?__expf(a3-m2):0.f);
    s2 += __shfl_xor(s2, 16);
    s2 += __shfl_xor(s2, 32);
    float closs = -(m2 + __logf(s2));

    float s3 = (v0?__expf(ll[0])*pi[0]:0.f) + (v1?__expf(ll[1])*pi[1]:0.f)
             + (v2?__expf(ll[2])*pi[2]:0.f) + (v3?__expf(ll[3])*pi[3]:0.f);
    s3 += __shfl_xor(s3, 16);
    s3 += __shfl_xor(s3, 32);
    float prob = s3 / (d*d + 1e-10f);

    if (lane < 16 && mk) { accP += prob; accL += closs; accC += 1.f; }
  }

  accP += __shfl_xor(accP, 1); accP += __shfl_xor(accP, 2);
  accP += __shfl_xor(accP, 4); accP += __shfl_xor(accP, 8);
  accL += __shfl_xor(accL, 1); accL += __shfl_xor(accL, 2);
  accL += __shfl_xor(accL, 4); accL += __shfl_xor(accL, 8);
  accC += __shfl_xor(accC, 1); accC += __shfl_xor(accC, 2);
  accC += __shfl_xor(accC, 4); accC += __shfl_xor(accC, 8);
  if (lane == 0) { red[wave][0] = accP; red[wave][1] = accL; red[wave][2] = accC; }
  __syncthreads();
  if (tid == 0) {
    float sP = 0.f, sL = 0.f, sC = 0.f;
    for (int w = 0; w < WAVES; ++w) { sP += red[w][0]; sL += red[w][1]; sC += red[w][2]; }
    int b = (int)(((long)blockIdx.x * TPB) >> 13);
    atomicAdd(&out_score[b], sP);
    atomicAdd(&ws[0], sL);
    atomicAdd(&ws[1], sC);
  }
}

extern "C" void kernel_launch(void* const* d_in, const int* in_sizes, int n_in,
                              void* d_out, int out_size, void* d_ws, size_t ws_size,
                              hipStream_t stream) {
  const float* feat = (const float*)d_in[0];
  const float* dist = (const float*)d_in[1];
  const int* dmask = (const int*)d_in[2];
  float* out = (float*)d_out;
  float* ws  = (float*)d_ws;

  hipLaunchKernelGGL(init_kernel, dim3(1), dim3(64), 0, stream, out, ws);

  bool prep_ok = (ws_size >= (size_t)(WS_IMG_OFF + IMG_BYTES));
  if (prep_ok) {
    short* img = (short*)((char*)d_ws + WS_IMG_OFF);
    hipLaunchKernelGGL(prep_kernel, dim3(116), dim3(256), 0, stream,
        (const float*)d_in[3],  (const float*)d_in[4],  (const float*)d_in[5],  (const float*)d_in[6],
        (const float*)d_in[7],  (const float*)d_in[8],  (const float*)d_in[9],  (const float*)d_in[10],
        (const float*)d_in[11], (const float*)d_in[12], (const float*)d_in[13], (const float*)d_in[14],
        img);
    hipLaunchKernelGGL((rtm_main<1>), dim3(TOKS/TPB), dim3(THREADS), 0, stream,
        feat, dist, dmask, (const short*)img,
        (const float*)d_in[3],  (const float*)d_in[4],  (const float*)d_in[5],  (const float*)d_in[6],
        (const float*)d_in[7],  (const float*)d_in[8],  (const float*)d_in[9],  (const float*)d_in[10],
        (const float*)d_in[11], (const float*)d_in[12], (const float*)d_in[13], (const float*)d_in[14],
        out, ws);
  } else {
    hipLaunchKernelGGL((rtm_main<0>), dim3(TOKS/TPB), dim3(THREADS), 0, stream,
        feat, dist, dmask, (const short*)nullptr,
        (const float*)d_in[3],  (const float*)d_in[4],  (const float*)d_in[5],  (const float*)d_in[6],
        (const float*)d_in[7],  (const float*)d_in[8],  (const float*)d_in[9],  (const float*)d_in[10],
        (const float*)d_in[11], (const float*)d_in[12], (const float*)d_in[13], (const float*)d_in[14],
        out, ws);
  }

  hipLaunchKernelGGL(fin_kernel, dim3(1), dim3(64), 0, stream, out, ws);
}